// Round 18
// baseline (47.542 us; speedup 1.0000x reference)
//
#include <hip/hip_runtime.h>

namespace {

constexpr int   kT = 512, kC = 512, kL = 128, kBlank = 511;
constexpr int   kCH  = 16;         // rows per chunk
constexpr int   kNCH = kT / kCH;   // 32 chunks
constexpr float kEps = 1e-7f, kLn2 = 0.6931471805599453f;

typedef float __attribute__((address_space(1))) f32g;
typedef float __attribute__((address_space(3))) f32l;

__device__ __forceinline__ void glds16(const float* g, float* l) {
    __builtin_amdgcn_global_load_lds((const f32g*)g, (f32l*)l, 16, 0, 0);
}
__device__ __forceinline__ float rlane(float x, int l) {
    return __int_as_float(__builtin_amdgcn_readlane(__float_as_int(x), l));
}
// VALU-pipe lane shift: lane i <- lane i-1, lane 0 <- 0 (r17-proven).
__device__ __forceinline__ float dpp_shr1(float x) {
    return __int_as_float(__builtin_amdgcn_update_dpp(
        0, __float_as_int(x), 0x138 /*WAVE_SHR1*/, 0xF, 0xF, false));
}
__device__ __forceinline__ float LOG2(float x) { return __builtin_amdgcn_logf(x); }

__device__ __forceinline__ void barrier_raw() {
    asm volatile("" ::: "memory");
    __builtin_amdgcn_s_barrier();
    asm volatile("" ::: "memory");
}

__global__ __launch_bounds__(192, 1) void ctc_fwd_kernel(
        const int* __restrict__ labels,
        const float* __restrict__ y_pred,
        float* __restrict__ out) {
    __shared__ __align__(16) float buf[4][kCH][kC];   // 128 KiB chunk ring

    const int tid  = (int)threadIdx.x;
    const int lane = tid & 63;
    const int wv   = tid >> 6;           // 0 = consumer, 1..2 = producers
    const int b    = (int)blockIdx.x;
    const float* yp  = y_pred + (size_t)b * kT * kC;
    const int*   lab = labels + b * kL;

    // consumer constants: state s = 4*lane + k (k=0..3), + scalar 256
    int   cls1 = kBlank, cls3 = kBlank;
    float skp1 = 0.f, skp3 = 0.f;
    if (wv == 0) {
        cls1 = lab[2 * lane];
        cls3 = lab[2 * lane + 1];
        skp1 = (lane >= 1 && lab[2 * lane] != lab[2 * lane - 1]) ? 1.f : 0.f;
        skp3 = (lab[2 * lane + 1] != lab[2 * lane]) ? 1.f : 0.f;
    }
    const int r0 = (wv - 1) * 8;         // producer wave's 8 rows of each chunk

    // ping-pong per-chunk register caches (consumer)
    float gA_rb[kCH], gA_r1[kCH], gA_r3[kCH];
    float gB_rb[kCH], gB_r1[kCH], gB_r3[kCH];

    // rotating ring pointers: bC = slot chunk c, bN = c+1, bP2 = c+2, bP3 = c+3
    float (*bC)[kC]  = buf[0];
    float (*bN)[kC]  = buf[1];
    float (*bP2)[kC] = buf[2];
    float (*bP3)[kC] = buf[3];

    // ---- prologue: producers issue chunks 0..3 (16 loads/chunk/wave, FIFO
    //      order), then wait vmcnt(32) -> chunks 0,1 resident ----
    if (wv >= 1) {
        for (int ch = 0; ch < 4; ++ch)
            for (int r = 0; r < 8; ++r) {
                const float* row = yp + (size_t)(ch * kCH + r0 + r) * kC;
                glds16(row + lane * 4,       &buf[ch][r0 + r][0]);
                glds16(row + 256 + lane * 4, &buf[ch][r0 + r][256]);
            }
        asm volatile("s_waitcnt vmcnt(32)" ::: "memory");
    }
    barrier_raw();
    if (wv == 0) {   // pre-gather chunk 0 into gA
#pragma unroll
        for (int r = 0; r < kCH; ++r) {
            gA_rb[r] = bC[r][kBlank];
            gA_r1[r] = bC[r][cls1];
            gA_r3[r] = bC[r][cls3];
        }
        asm volatile("s_waitcnt lgkmcnt(0)" ::: "memory");
    }
    barrier_raw();   // chunk-0 slot now safe to overwrite (iter 0 producers)

    float a0 = 0.f, a1 = 0.f, a2 = 0.f, a3 = 0.f, a256 = 0.f, etot = 0.f;
    float inj = (lane == 0) ? 1.f : 0.f;

    // One chunk. Producers: issue chunk c+4 into slot of chunk c (freed:
    // consumer gathered chunk c last iter), wait vmcnt(32) -> c+2 resident,
    // 2 chunks stay in flight across the barrier. Consumer: r17 body.
#define CHUNK_BODY(C_, CUR, NXT, GATHER_)                                     \
    {                                                                         \
        if (wv >= 1) {                                                        \
            if ((C_) + 4 < kNCH) {                                            \
                for (int r = 0; r < 8; ++r) {                                 \
                    const float* row = yp + (size_t)(((C_) + 4) * kCH + r0 + r) * kC; \
                    glds16(row + lane * 4,       &bC[r0 + r][0]);             \
                    glds16(row + 256 + lane * 4, &bC[r0 + r][256]);           \
                }                                                             \
                asm volatile("s_waitcnt vmcnt(32)" ::: "memory");             \
            } else if ((C_) == kNCH - 4) {                                    \
                asm volatile("s_waitcnt vmcnt(16)" ::: "memory");             \
            } else if ((C_) == kNCH - 3) {                                    \
                asm volatile("s_waitcnt vmcnt(0)" ::: "memory");              \
            }                                                                 \
        } else {                                                              \
            _Pragma("unroll")                                                 \
            for (int r = 0; r < kCH; ++r) {                                   \
                float sh3 = dpp_shr1(a3);                                     \
                sh3 = (lane == 0) ? 0.f : sh3;                                \
                if (GATHER_) {                                                \
                    NXT##_rb[r] = bN[r][kBlank];                              \
                    NXT##_r1[r] = bN[r][cls1];                                \
                    NXT##_r3[r] = bN[r][cls3];                                \
                }                                                             \
                const float pb = CUR##_rb[r] + kEps;                          \
                const float p1 = CUR##_r1[r] + kEps;                          \
                const float p3 = CUR##_r3[r] + kEps;                          \
                const float a255 = rlane(a3, 63);                             \
                const float b0 = (a0 + sh3 + inj) * pb;                       \
                const float b1 = (a1 + a0 + skp1 * sh3 + inj) * p1;           \
                const float b2 = (a2 + a1) * pb;                              \
                const float b3 = (a3 + a2 + skp3 * a1) * p3;                  \
                a256 = (a256 + a255) * pb;                                    \
                a0 = b0; a1 = b1; a2 = b2; a3 = b3;                           \
                inj = 0.f;                                                    \
            }                                                                 \
            asm volatile("s_waitcnt lgkmcnt(0)" ::: "memory");                \
            if ((C_) & 1) {                                                   \
                float m = fmaxf(fmaxf(a0, a1), fmaxf(a2, a3));                \
                _Pragma("unroll")                                             \
                for (int i = 1; i < 64; i <<= 1) m = fmaxf(m, __shfl_xor(m, i)); \
                m = fmaxf(m, a256);                                           \
                const int ex = (__float_as_int(m) >> 23) & 0xFF;              \
                if (ex > 1) {                                                 \
                    const float sc = __int_as_float((254 - ex) << 23);        \
                    a0 *= sc; a1 *= sc; a2 *= sc; a3 *= sc; a256 *= sc;       \
                    etot += (float)(ex - 127);                                \
                }                                                             \
            }                                                                 \
        }                                                                     \
        barrier_raw();                                                        \
        float (*tmp_)[kC] = bC; bC = bN; bN = bP2; bP2 = bP3; bP3 = tmp_;     \
    }

    // main loop: chunk pairs c = 0..29 (gathers always valid: c+1 <= 30)
    for (int cp = 0; cp < 15; ++cp) {
        const int c = 2 * cp;
        CHUNK_BODY(c,     gA, gB, true);
        CHUNK_BODY(c + 1, gB, gA, true);
    }
    // peeled tail: c = 30 (gathers chunk 31), c = 31 (no gathers)
    CHUNK_BODY(30, gA, gB, true);
    CHUNK_BODY(31, gB, gA, false);
#undef CHUNK_BODY

    // ---- loss = -ln2 * (log2(alpha255 + alpha256) + etot) ----
    if (wv == 0) {
        const float a255 = rlane(a3, 63);
        const float s    = a255 + a256;
        const float loss = -kLn2 * (LOG2(s) + etot);
        if (lane == 0) out[b] = loss;
    }
}

} // namespace

extern "C" void kernel_launch(void* const* d_in, const int* in_sizes, int n_in,
                              void* d_out, int out_size, void* d_ws, size_t ws_size,
                              hipStream_t stream) {
    const int*   labels = (const int*)d_in[0];   // y_true [256,128] int32
    const float* y_pred = (const float*)d_in[1]; // y_pred [256,512,512] f32
    float*       out    = (float*)d_out;         // loss [256,1] f32
    (void)in_sizes; (void)n_in; (void)d_ws; (void)ws_size;
    hipLaunchKernelGGL(ctc_fwd_kernel, dim3(out_size), dim3(192), 0, stream,
                       labels, y_pred, out);
}